// Round 3
// baseline (923.632 us; speedup 1.0000x reference)
//
#include <hip/hip_runtime.h>

#define TOK 16384
#define DIM 2048
#define RED 1024
#define KCR 5120   // 5 * 1024 stacked cross K
#define NPOW 6

typedef __attribute__((ext_vector_type(8))) short short8v;
typedef __attribute__((ext_vector_type(8))) unsigned short u16x8;
typedef __attribute__((ext_vector_type(4))) float f32x4;

__device__ __forceinline__ unsigned short f2bf(float f) {
    union { float f; unsigned u; } v; v.f = f;
    unsigned r = v.u + 0x7fffu + ((v.u >> 16) & 1u);   // RNE
    return (unsigned short)(r >> 16);
}

// ---------------------------------------------------------------------------
// Transpose + fp32->bf16 convert: dst[c*dstride + slab*slabR + r] = src[slab][r][c]
// grid: (C/32, R/32, nslab), block (32,8)
// ---------------------------------------------------------------------------
__global__ __launch_bounds__(256)
void k_tcvt(const float* __restrict__ src, unsigned short* __restrict__ dst,
            int R, int C, int dstride, int slabR)
{
    __shared__ float tile[32][33];
    const int c0 = blockIdx.x * 32, r0 = blockIdx.y * 32;
    const int slab = blockIdx.z;
    src += (size_t)slab * R * C;
    const int x = threadIdx.x, y0 = threadIdx.y;
#pragma unroll
    for (int dy = 0; dy < 32; dy += 8)
        tile[y0 + dy][x] = src[(size_t)(r0 + y0 + dy) * C + c0 + x];
    __syncthreads();
#pragma unroll
    for (int dy = 0; dy < 32; dy += 8) {
        const int c = c0 + y0 + dy;
        dst[(size_t)c * dstride + slab * slabR + r0 + x] = f2bf(tile[x][y0 + dy]);
    }
}

// ---------------------------------------------------------------------------
// GEMM 1: H = X(fp32) @ down_wT(bf16)^T + down_b   -> H fp32 [TOK][RED]
// 128x128 tile, BK=32, 4 waves 2x2, mfma_f32_16x16x32_bf16
// ---------------------------------------------------------------------------
__global__ __launch_bounds__(256)
void k_down(const float* __restrict__ X, const unsigned short* __restrict__ BT,
            const float* __restrict__ bias, float* __restrict__ H)
{
    __shared__ unsigned short As[128][40];
    __shared__ unsigned short Bs[128][40];
    const int tid = threadIdx.x;
    const int bm = blockIdx.x * 128, bn = blockIdx.y * 128;
    const int srow = tid >> 1, skq = (tid & 1) << 4;
    const int lane = tid & 63, wave = tid >> 6;
    const int wm = (wave >> 1) << 6, wn = (wave & 1) << 6;
    const int fr = lane & 15, lg = lane >> 4;

    f32x4 acc[4][4] = {};
    const float* ap = X + (size_t)(bm + srow) * DIM + skq;
    const unsigned short* bp = BT + (size_t)(bn + srow) * DIM + skq;

    for (int kb = 0; kb < DIM; kb += 32) {
        float4 a0 = *(const float4*)(ap + kb);
        float4 a1 = *(const float4*)(ap + kb + 4);
        float4 a2 = *(const float4*)(ap + kb + 8);
        float4 a3 = *(const float4*)(ap + kb + 12);
        u16x8 b0 = *(const u16x8*)(bp + kb);
        u16x8 b1 = *(const u16x8*)(bp + kb + 8);
        u16x8 p0, p1;
        p0[0] = f2bf(a0.x); p0[1] = f2bf(a0.y); p0[2] = f2bf(a0.z); p0[3] = f2bf(a0.w);
        p0[4] = f2bf(a1.x); p0[5] = f2bf(a1.y); p0[6] = f2bf(a1.z); p0[7] = f2bf(a1.w);
        p1[0] = f2bf(a2.x); p1[1] = f2bf(a2.y); p1[2] = f2bf(a2.z); p1[3] = f2bf(a2.w);
        p1[4] = f2bf(a3.x); p1[5] = f2bf(a3.y); p1[6] = f2bf(a3.z); p1[7] = f2bf(a3.w);
        __syncthreads();
        *(u16x8*)&As[srow][skq]     = p0;
        *(u16x8*)&As[srow][skq + 8] = p1;
        *(u16x8*)&Bs[srow][skq]     = b0;
        *(u16x8*)&Bs[srow][skq + 8] = b1;
        __syncthreads();
        short8v af[4], bfv[4];
#pragma unroll
        for (int mi = 0; mi < 4; ++mi)
            af[mi] = *(const short8v*)&As[wm + mi * 16 + fr][lg * 8];
#pragma unroll
        for (int ni = 0; ni < 4; ++ni)
            bfv[ni] = *(const short8v*)&Bs[wn + ni * 16 + fr][lg * 8];
#pragma unroll
        for (int mi = 0; mi < 4; ++mi)
#pragma unroll
            for (int ni = 0; ni < 4; ++ni)
                acc[mi][ni] = __builtin_amdgcn_mfma_f32_16x16x32_bf16(
                    af[mi], bfv[ni], acc[mi][ni], 0, 0, 0);
    }
#pragma unroll
    for (int ni = 0; ni < 4; ++ni) {
        const int col = bn + wn + ni * 16 + fr;
        const float bv = bias[col];
#pragma unroll
        for (int mi = 0; mi < 4; ++mi)
#pragma unroll
            for (int j = 0; j < 4; ++j) {
                const int row = bm + wm + mi * 16 + lg * 4 + j;
                H[(size_t)row * RED + col] = acc[mi][ni][j] + bv;
            }
    }
}

// ---------------------------------------------------------------------------
// GEMM 2: stacked-K cross. A'[m, i*1024+r] = H[m,r]^(i+1) (fp32->bf16 on the
// fly), B' = crossT bf16 [RED][KCR]. Epilogue: ACC = poly(h) + gemm*h -> bf16
// ---------------------------------------------------------------------------
__global__ __launch_bounds__(256)
void k_cross(const float* __restrict__ H, const unsigned short* __restrict__ CT,
             const float* __restrict__ coeffs, unsigned short* __restrict__ ACCb)
{
    __shared__ unsigned short As[128][40];
    __shared__ unsigned short Bs[128][40];
    const int tid = threadIdx.x;
    const int bm = blockIdx.x * 128, bn = blockIdx.y * 128;
    const int srow = tid >> 1, skq = (tid & 1) << 4;
    const int lane = tid & 63, wave = tid >> 6;
    const int wm = (wave >> 1) << 6, wn = (wave & 1) << 6;
    const int fr = lane & 15, lg = lane >> 4;

    f32x4 acc[4][4] = {};
    const float* hp = H + (size_t)(bm + srow) * RED + skq;
    const unsigned short* bp = CT + (size_t)(bn + srow) * KCR + skq;

    for (int kb = 0; kb < KCR; kb += 32) {
        const int p = kb >> 10;          // extra multiplies: power = p+1
        const int r = kb & 1023;
        float4 a0 = *(const float4*)(hp + r);
        float4 a1 = *(const float4*)(hp + r + 4);
        float4 a2 = *(const float4*)(hp + r + 8);
        float4 a3 = *(const float4*)(hp + r + 12);
        u16x8 b0 = *(const u16x8*)(bp + kb);
        u16x8 b1 = *(const u16x8*)(bp + kb + 8);
        float vv[16] = {a0.x, a0.y, a0.z, a0.w, a1.x, a1.y, a1.z, a1.w,
                        a2.x, a2.y, a2.z, a2.w, a3.x, a3.y, a3.z, a3.w};
        u16x8 p0, p1;
#pragma unroll
        for (int j = 0; j < 8; ++j) {
            float v = vv[j], pw = v;
            for (int t = 0; t < p; ++t) pw *= v;
            p0[j] = f2bf(pw);
        }
#pragma unroll
        for (int j = 0; j < 8; ++j) {
            float v = vv[8 + j], pw = v;
            for (int t = 0; t < p; ++t) pw *= v;
            p1[j] = f2bf(pw);
        }
        __syncthreads();
        *(u16x8*)&As[srow][skq]     = p0;
        *(u16x8*)&As[srow][skq + 8] = p1;
        *(u16x8*)&Bs[srow][skq]     = b0;
        *(u16x8*)&Bs[srow][skq + 8] = b1;
        __syncthreads();
        short8v af[4], bfv[4];
#pragma unroll
        for (int mi = 0; mi < 4; ++mi)
            af[mi] = *(const short8v*)&As[wm + mi * 16 + fr][lg * 8];
#pragma unroll
        for (int ni = 0; ni < 4; ++ni)
            bfv[ni] = *(const short8v*)&Bs[wn + ni * 16 + fr][lg * 8];
#pragma unroll
        for (int mi = 0; mi < 4; ++mi)
#pragma unroll
            for (int ni = 0; ni < 4; ++ni)
                acc[mi][ni] = __builtin_amdgcn_mfma_f32_16x16x32_bf16(
                    af[mi], bfv[ni], acc[mi][ni], 0, 0, 0);
    }
    // epilogue: out = sum_d coeffs[d]*h^(d+1) + gemm*h, store bf16
#pragma unroll
    for (int ni = 0; ni < 4; ++ni) {
        const int col = bn + wn + ni * 16 + fr;
        float cf[NPOW];
#pragma unroll
        for (int d = 0; d < NPOW; ++d) cf[d] = coeffs[d * RED + col];
#pragma unroll
        for (int mi = 0; mi < 4; ++mi)
#pragma unroll
            for (int j = 0; j < 4; ++j) {
                const int row = bm + wm + mi * 16 + lg * 4 + j;
                const float h = H[(size_t)row * RED + col];
                float poly = 0.f, pw = h;
#pragma unroll
                for (int d = 0; d < NPOW; ++d) { poly += pw * cf[d]; pw *= h; }
                ACCb[(size_t)row * RED + col] = f2bf(poly + acc[mi][ni][j] * h);
            }
    }
}

// ---------------------------------------------------------------------------
// GEMM 3: OUT = ACCb(bf16) @ up_wT(bf16)^T + up_b + X   -> fp32 [TOK][DIM]
// ---------------------------------------------------------------------------
__global__ __launch_bounds__(256)
void k_up(const unsigned short* __restrict__ A, const unsigned short* __restrict__ BT,
          const float* __restrict__ bias, const float* __restrict__ X,
          float* __restrict__ OUT)
{
    __shared__ unsigned short As[128][40];
    __shared__ unsigned short Bs[128][40];
    const int tid = threadIdx.x;
    const int bm = blockIdx.x * 128, bn = blockIdx.y * 128;
    const int srow = tid >> 1, skq = (tid & 1) << 4;
    const int lane = tid & 63, wave = tid >> 6;
    const int wm = (wave >> 1) << 6, wn = (wave & 1) << 6;
    const int fr = lane & 15, lg = lane >> 4;

    f32x4 acc[4][4] = {};
    const unsigned short* ap = A + (size_t)(bm + srow) * RED + skq;
    const unsigned short* bp = BT + (size_t)(bn + srow) * RED + skq;

    for (int kb = 0; kb < RED; kb += 32) {
        u16x8 a0 = *(const u16x8*)(ap + kb);
        u16x8 a1 = *(const u16x8*)(ap + kb + 8);
        u16x8 b0 = *(const u16x8*)(bp + kb);
        u16x8 b1 = *(const u16x8*)(bp + kb + 8);
        __syncthreads();
        *(u16x8*)&As[srow][skq]     = a0;
        *(u16x8*)&As[srow][skq + 8] = a1;
        *(u16x8*)&Bs[srow][skq]     = b0;
        *(u16x8*)&Bs[srow][skq + 8] = b1;
        __syncthreads();
        short8v af[4], bfv[4];
#pragma unroll
        for (int mi = 0; mi < 4; ++mi)
            af[mi] = *(const short8v*)&As[wm + mi * 16 + fr][lg * 8];
#pragma unroll
        for (int ni = 0; ni < 4; ++ni)
            bfv[ni] = *(const short8v*)&Bs[wn + ni * 16 + fr][lg * 8];
#pragma unroll
        for (int mi = 0; mi < 4; ++mi)
#pragma unroll
            for (int ni = 0; ni < 4; ++ni)
                acc[mi][ni] = __builtin_amdgcn_mfma_f32_16x16x32_bf16(
                    af[mi], bfv[ni], acc[mi][ni], 0, 0, 0);
    }
#pragma unroll
    for (int ni = 0; ni < 4; ++ni) {
        const int col = bn + wn + ni * 16 + fr;
        const float bv = bias[col];
#pragma unroll
        for (int mi = 0; mi < 4; ++mi)
#pragma unroll
            for (int j = 0; j < 4; ++j) {
                const int row = bm + wm + mi * 16 + lg * 4 + j;
                OUT[(size_t)row * DIM + col] =
                    acc[mi][ni][j] + bv + X[(size_t)row * DIM + col];
            }
    }
}

extern "C" void kernel_launch(void* const* d_in, const int* in_sizes, int n_in,
                              void* d_out, int out_size, void* d_ws, size_t ws_size,
                              hipStream_t stream) {
    const float* x      = (const float*)d_in[0];
    const float* down_w = (const float*)d_in[1];
    const float* down_b = (const float*)d_in[2];
    const float* coeffs = (const float*)d_in[3];
    const float* cross  = (const float*)d_in[4];
    const float* up_w   = (const float*)d_in[5];
    const float* up_b   = (const float*)d_in[6];
    float* out = (float*)d_out;

    unsigned char* w = (unsigned char*)d_ws;
    float*          H      = (float*)w;                                   // 64 MB
    unsigned short* ACCb   = (unsigned short*)(w + 67108864ull);          // 32 MB
    unsigned short* downT  = (unsigned short*)(w + 67108864ull + 33554432ull); // [RED][DIM] bf16
    unsigned short* crossT = downT + (size_t)RED * DIM;                   // [RED][KCR] bf16
    unsigned short* upT    = crossT + (size_t)RED * KCR;                  // [DIM][RED] bf16

    // weight transpose+convert
    k_tcvt<<<dim3(RED / 32, DIM / 32, 1), dim3(32, 8), 0, stream>>>(
        down_w, downT, DIM, RED, DIM, 0);
    k_tcvt<<<dim3(RED / 32, RED / 32, 5), dim3(32, 8), 0, stream>>>(
        cross, crossT, RED, RED, KCR, RED);
    k_tcvt<<<dim3(DIM / 32, RED / 32, 1), dim3(32, 8), 0, stream>>>(
        up_w, upT, RED, DIM, RED, 0);

    k_down <<<dim3(TOK / 128, RED / 128), 256, 0, stream>>>(x, downT, down_b, H);
    k_cross<<<dim3(TOK / 128, RED / 128), 256, 0, stream>>>(H, crossT, coeffs, ACCb);
    k_up   <<<dim3(TOK / 128, DIM / 128), 256, 0, stream>>>(ACCb, upT, up_b, x, out);
}

// Round 5
// 747.828 us; speedup vs baseline: 1.2351x; 1.2351x over previous
//
#include <hip/hip_runtime.h>
#include <hip/hip_bf16.h>

#define TOK 16384
#define DIM 2048
#define RED 1024
#define KCR 5120   // 5 * 1024 stacked cross K
#define NPOW 6

typedef __attribute__((ext_vector_type(8))) short short8v;
typedef __attribute__((ext_vector_type(8))) unsigned short u16x8;
typedef __attribute__((ext_vector_type(4))) float f32x4;

__device__ __forceinline__ unsigned short f2bf(float f) {
    return __builtin_bit_cast(unsigned short, __float2bfloat16(f));
}

// ---------------------------------------------------------------------------
// Transpose + fp32->bf16 convert: dst[c*dstride + slab*slabR + r] = src[slab][r][c]
// ---------------------------------------------------------------------------
__global__ __launch_bounds__(256)
void k_tcvt(const float* __restrict__ src, unsigned short* __restrict__ dst,
            int R, int C, int dstride, int slabR)
{
    __shared__ float tile[32][33];
    const int c0 = blockIdx.x * 32, r0 = blockIdx.y * 32;
    const int slab = blockIdx.z;
    src += (size_t)slab * R * C;
    const int x = threadIdx.x, y0 = threadIdx.y;
#pragma unroll
    for (int dy = 0; dy < 32; dy += 8)
        tile[y0 + dy][x] = src[(size_t)(r0 + y0 + dy) * C + c0 + x];
    __syncthreads();
#pragma unroll
    for (int dy = 0; dy < 32; dy += 8) {
        const int c = c0 + y0 + dy;
        dst[(size_t)c * dstride + slab * slabR + r0 + x] = f2bf(tile[x][y0 + dy]);
    }
}

// ---------------------------------------------------------------------------
// GEMM 1: H = X(fp32) @ down_wT(bf16)^T + down_b   -> H fp32 [TOK][RED]
// ---------------------------------------------------------------------------
__global__ __launch_bounds__(256)
void k_down(const float* __restrict__ X, const unsigned short* __restrict__ BT,
            const float* __restrict__ bias, float* __restrict__ H)
{
    __shared__ unsigned short As[128][40];
    __shared__ unsigned short Bs[128][40];
    const int tid = threadIdx.x;
    const int bid = blockIdx.x;
    const int bm = (bid >> 3) * 128, bn = (bid & 7) * 128;   // N-fast: share X slab
    const int srow = tid >> 1, skq = (tid & 1) << 4;
    const int lane = tid & 63, wave = tid >> 6;
    const int wm = (wave >> 1) << 6, wn = (wave & 1) << 6;
    const int fr = lane & 15, lg = lane >> 4;

    f32x4 acc[4][4] = {};
    const float* ap = X + (size_t)(bm + srow) * DIM + skq;
    const unsigned short* bp = BT + (size_t)(bn + srow) * DIM + skq;

    for (int kb = 0; kb < DIM; kb += 32) {
        float4 a0 = *(const float4*)(ap + kb);
        float4 a1 = *(const float4*)(ap + kb + 4);
        float4 a2 = *(const float4*)(ap + kb + 8);
        float4 a3 = *(const float4*)(ap + kb + 12);
        u16x8 b0 = *(const u16x8*)(bp + kb);
        u16x8 b1 = *(const u16x8*)(bp + kb + 8);
        u16x8 p0, p1;
        p0[0] = f2bf(a0.x); p0[1] = f2bf(a0.y); p0[2] = f2bf(a0.z); p0[3] = f2bf(a0.w);
        p0[4] = f2bf(a1.x); p0[5] = f2bf(a1.y); p0[6] = f2bf(a1.z); p0[7] = f2bf(a1.w);
        p1[0] = f2bf(a2.x); p1[1] = f2bf(a2.y); p1[2] = f2bf(a2.z); p1[3] = f2bf(a2.w);
        p1[4] = f2bf(a3.x); p1[5] = f2bf(a3.y); p1[6] = f2bf(a3.z); p1[7] = f2bf(a3.w);
        __syncthreads();
        *(u16x8*)&As[srow][skq]     = p0;
        *(u16x8*)&As[srow][skq + 8] = p1;
        *(u16x8*)&Bs[srow][skq]     = b0;
        *(u16x8*)&Bs[srow][skq + 8] = b1;
        __syncthreads();
        short8v af[4], bfv[4];
#pragma unroll
        for (int mi = 0; mi < 4; ++mi)
            af[mi] = *(const short8v*)&As[wm + mi * 16 + fr][lg * 8];
#pragma unroll
        for (int ni = 0; ni < 4; ++ni)
            bfv[ni] = *(const short8v*)&Bs[wn + ni * 16 + fr][lg * 8];
#pragma unroll
        for (int mi = 0; mi < 4; ++mi)
#pragma unroll
            for (int ni = 0; ni < 4; ++ni)
                acc[mi][ni] = __builtin_amdgcn_mfma_f32_16x16x32_bf16(
                    af[mi], bfv[ni], acc[mi][ni], 0, 0, 0);
    }
#pragma unroll
    for (int ni = 0; ni < 4; ++ni) {
        const int col = bn + wn + ni * 16 + fr;
        const float bv = bias[col];
#pragma unroll
        for (int mi = 0; mi < 4; ++mi)
#pragma unroll
            for (int j = 0; j < 4; ++j) {
                const int row = bm + wm + mi * 16 + lg * 4 + j;
                H[(size_t)row * RED + col] = acc[mi][ni][j] + bv;
            }
    }
}

// ---------------------------------------------------------------------------
// GEMM 2: stacked-K cross, power-pair reordering. 3 passes over powers
// {h^1,h^2}, {h^3,h^4}, {h^5}; per rb-step stage 2 K-chunks -> 32 MFMA / 2 barriers.
// Epilogue: ACC = poly(h) + gemm*h -> bf16
// ---------------------------------------------------------------------------
__global__ __launch_bounds__(256)
void k_cross(const float* __restrict__ H, const unsigned short* __restrict__ CT,
             const float* __restrict__ coeffs, unsigned short* __restrict__ ACCb)
{
    __shared__ unsigned short As[128][84];   // chunk0 @ col 0, chunk1 @ col 40
    __shared__ unsigned short Bs[128][84];
    const int tid = threadIdx.x;
    const int bid = blockIdx.x;
    const int bm = (bid >> 3) * 128;
    const int bn = (bid & 7) * 128;          // N-fast: consecutive blocks share H slab
    const int srow = tid >> 1, sc = (tid & 1) << 4;
    const int lane = tid & 63, wave = tid >> 6;
    const int wm = (wave >> 1) << 6, wn = (wave & 1) << 6;
    const int fr = lane & 15, lg = lane >> 4;

    f32x4 acc[4][4] = {};
    const float* hp = H + (size_t)(bm + srow) * RED + sc;
    const unsigned short* bp = CT + (size_t)(bn + srow) * KCR + sc;

    for (int g = 0; g < 3; ++g) {
        const bool two = (g < 2);
        const unsigned short* bp0 = bp + (2 * g) * RED;
        const unsigned short* bp1 = bp + (2 * g + 1) * RED;
        for (int rb = 0; rb < RED; rb += 32) {
            float4 h0 = *(const float4*)(hp + rb);
            float4 h1 = *(const float4*)(hp + rb + 4);
            float4 h2 = *(const float4*)(hp + rb + 8);
            float4 h3 = *(const float4*)(hp + rb + 12);
            u16x8 b00 = *(const u16x8*)(bp0 + rb);
            u16x8 b01 = *(const u16x8*)(bp0 + rb + 8);
            u16x8 b10 = {}, b11 = {};
            if (two) {
                b10 = *(const u16x8*)(bp1 + rb);
                b11 = *(const u16x8*)(bp1 + rb + 8);
            }
            const float v[16] = {h0.x, h0.y, h0.z, h0.w, h1.x, h1.y, h1.z, h1.w,
                                 h2.x, h2.y, h2.z, h2.w, h3.x, h3.y, h3.z, h3.w};
            u16x8 pa0, pa1, pb0, pb1;
#pragma unroll
            for (int j = 0; j < 16; ++j) {
                const float x = v[j];
                float a, b;
                if (g == 0)      { a = x;                  b = x * x; }
                else if (g == 1) { const float x2 = x * x; a = x2 * x;      b = x2 * x2; }
                else             { const float x2 = x * x; a = x2 * x2 * x; b = 0.f; }
                const unsigned short ua = f2bf(a), ub = f2bf(b);
                if (j < 8) { pa0[j] = ua;     pb0[j] = ub; }
                else       { pa1[j - 8] = ua; pb1[j - 8] = ub; }
            }
            __syncthreads();
            *(u16x8*)&As[srow][sc]     = pa0;
            *(u16x8*)&As[srow][sc + 8] = pa1;
            *(u16x8*)&Bs[srow][sc]     = b00;
            *(u16x8*)&Bs[srow][sc + 8] = b01;
            if (two) {
                *(u16x8*)&As[srow][40 + sc]     = pb0;
                *(u16x8*)&As[srow][40 + sc + 8] = pb1;
                *(u16x8*)&Bs[srow][40 + sc]     = b10;
                *(u16x8*)&Bs[srow][40 + sc + 8] = b11;
            }
            __syncthreads();
            {
                short8v afv[4], bfv[4];
#pragma unroll
                for (int mi = 0; mi < 4; ++mi)
                    afv[mi] = *(const short8v*)&As[wm + mi * 16 + fr][lg * 8];
#pragma unroll
                for (int ni = 0; ni < 4; ++ni)
                    bfv[ni] = *(const short8v*)&Bs[wn + ni * 16 + fr][lg * 8];
#pragma unroll
                for (int mi = 0; mi < 4; ++mi)
#pragma unroll
                    for (int ni = 0; ni < 4; ++ni)
                        acc[mi][ni] = __builtin_amdgcn_mfma_f32_16x16x32_bf16(
                            afv[mi], bfv[ni], acc[mi][ni], 0, 0, 0);
            }
            if (two) {
                short8v afv[4], bfv[4];
#pragma unroll
                for (int mi = 0; mi < 4; ++mi)
                    afv[mi] = *(const short8v*)&As[wm + mi * 16 + fr][40 + lg * 8];
#pragma unroll
                for (int ni = 0; ni < 4; ++ni)
                    bfv[ni] = *(const short8v*)&Bs[wn + ni * 16 + fr][40 + lg * 8];
#pragma unroll
                for (int mi = 0; mi < 4; ++mi)
#pragma unroll
                    for (int ni = 0; ni < 4; ++ni)
                        acc[mi][ni] = __builtin_amdgcn_mfma_f32_16x16x32_bf16(
                            afv[mi], bfv[ni], acc[mi][ni], 0, 0, 0);
            }
        }
    }
    // epilogue: out = sum_d coeffs[d]*h^(d+1) + gemm*h, store bf16
#pragma unroll
    for (int ni = 0; ni < 4; ++ni) {
        const int col = bn + wn + ni * 16 + fr;
        float cf[NPOW];
#pragma unroll
        for (int d = 0; d < NPOW; ++d) cf[d] = coeffs[d * RED + col];
#pragma unroll
        for (int mi = 0; mi < 4; ++mi)
#pragma unroll
            for (int j = 0; j < 4; ++j) {
                const int row = bm + wm + mi * 16 + lg * 4 + j;
                const float h = H[(size_t)row * RED + col];
                float poly = 0.f, pw = h;
#pragma unroll
                for (int d = 0; d < NPOW; ++d) { poly += pw * cf[d]; pw *= h; }
                ACCb[(size_t)row * RED + col] = f2bf(poly + acc[mi][ni][j] * h);
            }
    }
}

// ---------------------------------------------------------------------------
// GEMM 3: OUT = ACCb(bf16) @ up_wT(bf16)^T + up_b + X   -> fp32 [TOK][DIM]
// ---------------------------------------------------------------------------
__global__ __launch_bounds__(256)
void k_up(const unsigned short* __restrict__ A, const unsigned short* __restrict__ BT,
          const float* __restrict__ bias, const float* __restrict__ X,
          float* __restrict__ OUT)
{
    __shared__ unsigned short As[128][40];
    __shared__ unsigned short Bs[128][40];
    const int tid = threadIdx.x;
    const int bid = blockIdx.x;
    const int bm = (bid >> 4) * 128, bn = (bid & 15) * 128;  // N-fast: share ACC slab
    const int srow = tid >> 1, skq = (tid & 1) << 4;
    const int lane = tid & 63, wave = tid >> 6;
    const int wm = (wave >> 1) << 6, wn = (wave & 1) << 6;
    const int fr = lane & 15, lg = lane >> 4;

    f32x4 acc[4][4] = {};
    const unsigned short* ap = A + (size_t)(bm + srow) * RED + skq;
    const unsigned short* bp = BT + (size_t)(bn + srow) * RED + skq;

    for (int kb = 0; kb < RED; kb += 32) {
        u16x8 a0 = *(const u16x8*)(ap + kb);
        u16x8 a1 = *(const u16x8*)(ap + kb + 8);
        u16x8 b0 = *(const u16x8*)(bp + kb);
        u16x8 b1 = *(const u16x8*)(bp + kb + 8);
        __syncthreads();
        *(u16x8*)&As[srow][skq]     = a0;
        *(u16x8*)&As[srow][skq + 8] = a1;
        *(u16x8*)&Bs[srow][skq]     = b0;
        *(u16x8*)&Bs[srow][skq + 8] = b1;
        __syncthreads();
        short8v af[4], bfv[4];
#pragma unroll
        for (int mi = 0; mi < 4; ++mi)
            af[mi] = *(const short8v*)&As[wm + mi * 16 + fr][lg * 8];
#pragma unroll
        for (int ni = 0; ni < 4; ++ni)
            bfv[ni] = *(const short8v*)&Bs[wn + ni * 16 + fr][lg * 8];
#pragma unroll
        for (int mi = 0; mi < 4; ++mi)
#pragma unroll
            for (int ni = 0; ni < 4; ++ni)
                acc[mi][ni] = __builtin_amdgcn_mfma_f32_16x16x32_bf16(
                    af[mi], bfv[ni], acc[mi][ni], 0, 0, 0);
    }
#pragma unroll
    for (int ni = 0; ni < 4; ++ni) {
        const int col = bn + wn + ni * 16 + fr;
        const float bv = bias[col];
#pragma unroll
        for (int mi = 0; mi < 4; ++mi)
#pragma unroll
            for (int j = 0; j < 4; ++j) {
                const int row = bm + wm + mi * 16 + lg * 4 + j;
                OUT[(size_t)row * DIM + col] =
                    acc[mi][ni][j] + bv + X[(size_t)row * DIM + col];
            }
    }
}

extern "C" void kernel_launch(void* const* d_in, const int* in_sizes, int n_in,
                              void* d_out, int out_size, void* d_ws, size_t ws_size,
                              hipStream_t stream) {
    const float* x      = (const float*)d_in[0];
    const float* down_w = (const float*)d_in[1];
    const float* down_b = (const float*)d_in[2];
    const float* coeffs = (const float*)d_in[3];
    const float* cross  = (const float*)d_in[4];
    const float* up_w   = (const float*)d_in[5];
    const float* up_b   = (const float*)d_in[6];
    float* out = (float*)d_out;

    unsigned char* w = (unsigned char*)d_ws;
    float*          H      = (float*)w;                                        // 64 MB
    unsigned short* ACCb   = (unsigned short*)(w + 67108864ull);               // 32 MB
    unsigned short* downT  = (unsigned short*)(w + 67108864ull + 33554432ull); // [RED][DIM]
    unsigned short* crossT = downT + (size_t)RED * DIM;                        // [RED][KCR]
    unsigned short* upT    = crossT + (size_t)RED * KCR;                       // [DIM][RED]

    k_tcvt<<<dim3(RED / 32, DIM / 32, 1), dim3(32, 8), 0, stream>>>(
        down_w, downT, DIM, RED, DIM, 0);
    k_tcvt<<<dim3(RED / 32, RED / 32, 5), dim3(32, 8), 0, stream>>>(
        cross, crossT, RED, RED, KCR, RED);
    k_tcvt<<<dim3(DIM / 32, RED / 32, 1), dim3(32, 8), 0, stream>>>(
        up_w, upT, RED, DIM, RED, 0);

    k_down <<<TOK / 128 * (RED / 128), 256, 0, stream>>>(x, downT, down_b, H);
    k_cross<<<TOK / 128 * (RED / 128), 256, 0, stream>>>(H, crossT, coeffs, ACCb);
    k_up   <<<TOK / 128 * (DIM / 128), 256, 0, stream>>>(ACCb, upT, up_b, x, out);
}